// Round 2
// baseline (13303.757 us; speedup 1.0000x reference)
//
#include <hip/hip_runtime.h>

#define T_ 512
#define B_ 64
#define I_ 256
#define H_ 1024
#define G4_ 4096
#define O_ 256

#define NBLK 256
#define NTHR 512
#define GRP_BLKS 128
#define WPAD 1288   // 1280 + 8 pad (shorts): row stride 2576 B -> 4-bank step, 2-way conflict only

typedef short bfrag8 __attribute__((ext_vector_type(8)));   // 8 bf16 (4 VGPRs)
typedef float f32x4 __attribute__((ext_vector_type(4)));

// f32 -> bf16 bits, round-to-nearest-even
__device__ __forceinline__ unsigned short f2bf(float f) {
    unsigned int u = __builtin_bit_cast(unsigned int, f);
    u = (u + 0x7fffu + ((u >> 16) & 1u)) >> 16;
    return (unsigned short)u;
}

__device__ __forceinline__ float sigmoid_fast(float x) {
    return 1.0f / (1.0f + __expf(-x));     // x=-inf -> 1/inf = 0, no NaN
}
__device__ __forceinline__ float tanh_fast(float x) {
    x = fminf(fmaxf(x, -15.0f), 15.0f);    // avoid inf/inf
    float e = __expf(2.0f * x);
    return (e - 1.0f) / (e + 1.0f);
}

__global__ void cvt_bf16(const float* __restrict__ in, unsigned short* __restrict__ out, int n) {
    int i = blockIdx.x * blockDim.x + threadIdx.x;
    int st = gridDim.x * blockDim.x;
    for (; i < n; i += st) out[i] = f2bf(in[i]);
}

__global__ void bias_sum_k(const float* __restrict__ a, const float* __restrict__ b,
                           float* __restrict__ o, int n) {
    int i = blockIdx.x * blockDim.x + threadIdx.x;
    if (i < n) o[i] = a[i] + b[i];
}

// Persistent LSTM recurrence. 256 blocks x 512 threads (cooperative launch).
// Group g (bid>>7) owns batch rows [32g, 32g+32) — groups never synchronize.
// Block (lb = bid&127) owns h-columns [8*lb, 8*lb+8) x 4 gates = 32 gate-rows,
// whose W slice (32 x 1280 bf16) stays in LDS for all 512 steps.
// 8 waves: pair p=w&3 -> (mtile=p>>1, ntile=p&1); khalf=w>>2 splits K.
//   khalf0: h-K [0,512).  khalf1: h-K [512,1024) + x-K [0,256).
// Cell state c lives in a register of thread (b,j) = (tid>>3, tid&7) forever.
__global__ __launch_bounds__(NTHR, 1) void lstm_persist(
    const unsigned short* __restrict__ xbf,   // [T][B][I] bf16
    const unsigned short* __restrict__ whh,   // [4H][H] bf16
    const unsigned short* __restrict__ wih,   // [4H][I] bf16
    const float* __restrict__ bsum,           // [4H]
    unsigned short* __restrict__ hs,          // [T][B][H] bf16
    int* __restrict__ barcnt)                 // zeroed; 2 groups x 8 subcounters
{
    __shared__ unsigned short lds_w[32 * WPAD];   // 82,432 B
    __shared__ float glp[2][32][33];              //  8,448 B

    const int bid = blockIdx.x;
    const int gid = bid >> 7;
    const int lb  = bid & 127;
    const int cg0 = lb * 8;
    const int gb0 = gid * 32;
    const int tid = threadIdx.x;
    const int w   = tid >> 6;
    const int l   = tid & 63;
    const int l16 = l & 15;
    const int lk8 = (l >> 4) << 3;
    const int p     = w & 3;
    const int mtile = p >> 1;
    const int ntile = p & 1;
    const int khalf = w >> 2;

    // ---- stage W slice into LDS (once) ----
    for (int idx = tid; idx < 32 * 160; idx += NTHR) {
        int n  = idx / 160;          // local gate-row
        int kc = idx % 160;          // 8-elem chunk
        int grow = (n >> 3) * 1024 + cg0 + (n & 7);
        bfrag8 v;
        if (kc < 128) v = *(const bfrag8*)(whh + (size_t)grow * H_ + kc * 8);
        else          v = *(const bfrag8*)(wih + (size_t)grow * I_ + (kc - 128) * 8);
        *(bfrag8*)(lds_w + n * WPAD + kc * 8) = v;
    }

    // ---- per-thread pointwise state ----
    const int pb = tid >> 3, pj = tid & 7;
    float c_reg = 0.0f;
    float bias_g[4] = {0.f, 0.f, 0.f, 0.f};
    if (tid < 256) {
        #pragma unroll
        for (int g = 0; g < 4; ++g) bias_g[g] = bsum[g * 1024 + cg0 + pj];
    }
    __syncthreads();

    const int nrow = ntile * 16 + l16;                      // local gate-row (B frag)
    const unsigned short* __restrict__ wbase = lds_w + nrow * WPAD;
    const int arow = gb0 + mtile * 16 + l16;                // batch row (A frag)

    int* cnt = barcnt + gid * 256;   // 8 subcounters, 128 B apart

    for (int t = 0; t < T_; ++t) {
        f32x4 acc = {0.f, 0.f, 0.f, 0.f};

        if (khalf == 0) {
            if (t > 0) {
                const unsigned short* __restrict__ ap =
                    hs + (size_t)(t - 1) * (B_ * H_) + (size_t)arow * H_ + lk8;
                const unsigned short* __restrict__ wp = wbase + lk8;
                #pragma unroll
                for (int kt = 0; kt < 16; ++kt) {
                    bfrag8 a = *(const bfrag8*)(ap + kt * 32);
                    bfrag8 b = *(const bfrag8*)(wp + kt * 32);
                    acc = __builtin_amdgcn_mfma_f32_16x16x32_bf16(a, b, acc, 0, 0, 0);
                }
            }
        } else {
            if (t > 0) {
                const unsigned short* __restrict__ ap =
                    hs + (size_t)(t - 1) * (B_ * H_) + (size_t)arow * H_ + 512 + lk8;
                const unsigned short* __restrict__ wp = wbase + 512 + lk8;
                #pragma unroll
                for (int kt = 0; kt < 16; ++kt) {
                    bfrag8 a = *(const bfrag8*)(ap + kt * 32);
                    bfrag8 b = *(const bfrag8*)(wp + kt * 32);
                    acc = __builtin_amdgcn_mfma_f32_16x16x32_bf16(a, b, acc, 0, 0, 0);
                }
            }
            {   // x contribution (every step)
                const unsigned short* __restrict__ ap =
                    xbf + (size_t)t * (B_ * I_) + (size_t)arow * I_ + lk8;
                const unsigned short* __restrict__ wp = wbase + 1024 + lk8;
                #pragma unroll
                for (int kt = 0; kt < 8; ++kt) {
                    bfrag8 a = *(const bfrag8*)(ap + kt * 32);
                    bfrag8 b = *(const bfrag8*)(wp + kt * 32);
                    acc = __builtin_amdgcn_mfma_f32_16x16x32_bf16(a, b, acc, 0, 0, 0);
                }
            }
        }

        // ---- exchange partials, pointwise update ----
        const int mrow = (l >> 4) * 4;   // D: col=lane&15, row=(lane>>4)*4+reg [m89/m91]
        #pragma unroll
        for (int r = 0; r < 4; ++r)
            glp[khalf][mtile * 16 + mrow + r][ntile * 16 + l16] = acc[r];
        __syncthreads();

        if (tid < 256) {
            float pre[4];
            #pragma unroll
            for (int g = 0; g < 4; ++g) {
                int n = g * 8 + pj;
                pre[g] = glp[0][pb][n] + glp[1][pb][n] + bias_g[g];
            }
            float ig = sigmoid_fast(pre[0]);
            float fg = sigmoid_fast(pre[1]);
            float gg = tanh_fast(pre[2]);
            float og = sigmoid_fast(pre[3]);
            c_reg = fg * c_reg + ig * gg;
            float hn = og * tanh_fast(c_reg);
            hs[(size_t)t * (B_ * H_) + (size_t)(gb0 + pb) * H_ + cg0 + pj] = f2bf(hn);
        }
        __syncthreads();   // glp reads done; h writes issued

        // ---- group barrier: 8 distributed subcounters, monotonic targets ----
        if (w == 0) {
            if (l == 0) {
                __threadfence();   // make this block's h writes device-visible
                __hip_atomic_fetch_add(&cnt[(lb & 7) * 32], 1,
                                       __ATOMIC_RELEASE, __HIP_MEMORY_SCOPE_AGENT);
            }
            if (l < 8) {
                const int tgt = 16 * (t + 1);
                while (__hip_atomic_load(&cnt[l * 32],
                                         __ATOMIC_ACQUIRE, __HIP_MEMORY_SCOPE_AGENT) < tgt)
                    __builtin_amdgcn_s_sleep(1);
            }
            __threadfence();       // reader-side invalidate before hs[t] loads
        }
        __syncthreads();
    }
}

// out[TB][256] = hs[TB][1024] @ W_out[256][1024]^T + b_out
__global__ __launch_bounds__(256) void out_gemm(
    const unsigned short* __restrict__ hs,
    const unsigned short* __restrict__ wout,
    const float* __restrict__ bout,
    float* __restrict__ out)
{
    const int bid  = blockIdx.x;
    const int nblk = bid & 3;
    const int mblk = bid >> 2;
    const int tid  = threadIdx.x;
    const int w    = tid >> 6;
    const int l    = tid & 63;
    const int l16  = l & 15;
    const int lk8  = (l >> 4) << 3;

    const int m0 = mblk * 64 + w * 16;
    const int n0 = nblk * 64;

    f32x4 acc[4] = {};
    const unsigned short* __restrict__ arow = hs + (size_t)(m0 + l16) * H_;
#pragma unroll 2
    for (int kt = 0; kt < 32; ++kt) {
        int k = kt * 32 + lk8;
        bfrag8 af = *(const bfrag8*)(arow + k);
#pragma unroll
        for (int nt = 0; nt < 4; ++nt) {
            bfrag8 bf = *(const bfrag8*)(wout + (size_t)(n0 + nt * 16 + l16) * H_ + k);
            acc[nt] = __builtin_amdgcn_mfma_f32_16x16x32_bf16(af, bf, acc[nt], 0, 0, 0);
        }
    }
    const int mrow = (l >> 4) * 4;
#pragma unroll
    for (int nt = 0; nt < 4; ++nt) {
        int o = n0 + nt * 16 + l16;
        float bb = bout[o];
#pragma unroll
        for (int r = 0; r < 4; ++r) {
            out[(size_t)(m0 + mrow + r) * O_ + o] = acc[nt][r] + bb;
        }
    }
}

extern "C" void kernel_launch(void* const* d_in, const int* in_sizes, int n_in,
                              void* d_out, int out_size, void* d_ws, size_t ws_size,
                              hipStream_t stream) {
    const float* x     = (const float*)d_in[0];
    const float* W_ih  = (const float*)d_in[1];
    const float* W_hh  = (const float*)d_in[2];
    const float* b_ih  = (const float*)d_in[3];
    const float* b_hh  = (const float*)d_in[4];
    const float* W_out = (const float*)d_in[5];
    const float* b_out = (const float*)d_in[6];
    float* out = (float*)d_out;

    char* ws = (char*)d_ws;
    unsigned short* hs     = (unsigned short*)(ws);              // 67,108,864 B
    unsigned short* xbf    = (unsigned short*)(ws + 67108864);   // 16,777,216 B
    unsigned short* whh    = (unsigned short*)(ws + 83886080);   //  8,388,608 B
    unsigned short* wih    = (unsigned short*)(ws + 92274688);   //  2,097,152 B
    unsigned short* wout   = (unsigned short*)(ws + 94371840);   //    524,288 B
    float*          bsum   = (float*)         (ws + 94896128);   //     16,384 B
    int*            barcnt = (int*)           (ws + 94912512);   //      2,048 B

    cvt_bf16<<<2048, 256, 0, stream>>>(x,     xbf,  T_ * B_ * I_);
    cvt_bf16<<<2048, 256, 0, stream>>>(W_hh,  whh,  G4_ * H_);
    cvt_bf16<<<1024, 256, 0, stream>>>(W_ih,  wih,  G4_ * I_);
    cvt_bf16<<<256,  256, 0, stream>>>(W_out, wout, O_ * H_);
    bias_sum_k<<<16, 256, 0, stream>>>(b_ih, b_hh, bsum, G4_);
    hipMemsetAsync(barcnt, 0, 2048, stream);

    void* args[] = {(void*)&xbf, (void*)&whh, (void*)&wih, (void*)&bsum,
                    (void*)&hs, (void*)&barcnt};
    hipLaunchCooperativeKernel((const void*)lstm_persist, dim3(NBLK), dim3(NTHR),
                               args, 0, stream);

    out_gemm<<<2048, 256, 0, stream>>>(hs, wout, b_out, out);
}

// Round 4
// 3737.101 us; speedup vs baseline: 3.5599x; 3.5599x over previous
//
#include <hip/hip_runtime.h>

#define T_ 512
#define B_ 64
#define I_ 256
#define H_ 1024
#define G4_ 4096
#define O_ 256

#define NBLK 256
#define NTHR 512

typedef short bfrag8 __attribute__((ext_vector_type(8)));   // 8 bf16 (4 VGPRs)
typedef float f32x4 __attribute__((ext_vector_type(4)));
typedef unsigned int u32;

// f32 -> bf16 bits, round-to-nearest-even
__device__ __forceinline__ unsigned short f2bf(float f) {
    unsigned int u = __builtin_bit_cast(unsigned int, f);
    u = (u + 0x7fffu + ((u >> 16) & 1u)) >> 16;
    return (unsigned short)u;
}

__device__ __forceinline__ float sigmoid_fast(float x) {
    return 1.0f / (1.0f + __expf(-x));
}
__device__ __forceinline__ float tanh_fast(float x) {
    x = fminf(fmaxf(x, -15.0f), 15.0f);
    float e = __expf(2.0f * x);
    return (e - 1.0f) / (e + 1.0f);
}

// Coherence-point (write-through, cache-bypass) access helpers [gfx950 sc0 sc1]
__device__ __forceinline__ void store_wt_u32(u32* p, u32 v) {
    asm volatile("global_store_dword %0, %1, off sc0 sc1" :: "v"(p), "v"(v) : "memory");
}
__device__ __forceinline__ void poll2_u32(const u32* p0, const u32* p1, u32& a, u32& b) {
    asm volatile("global_load_dword %0, %2, off sc0 sc1\n\t"
                 "global_load_dword %1, %3, off sc0 sc1\n\t"
                 "s_waitcnt vmcnt(0)"
                 : "=&v"(a), "=&v"(b) : "v"(p0), "v"(p1) : "memory");
}

__global__ void cvt_bf16(const float* __restrict__ in, unsigned short* __restrict__ out, int n) {
    int i = blockIdx.x * blockDim.x + threadIdx.x;
    int st = gridDim.x * blockDim.x;
    for (; i < n; i += st) out[i] = f2bf(in[i]);
}

__global__ void bias_sum_k(const float* __restrict__ a, const float* __restrict__ b,
                           float* __restrict__ o, int n) {
    int i = blockIdx.x * blockDim.x + threadIdx.x;
    if (i < n) o[i] = a[i] + b[i];
}

// Persistent LSTM recurrence. 256 blocks x 512 threads (cooperative).
// Group g = bid>>7 owns batch rows [32g,32g+32); groups are independent.
// Block lb = bid&127 owns h-cols [8lb,8lb+8) x 4 gates = 32 gate-rows; that
// W slice lives in VGPRs (20 bfrag8/wave) for all T.
// 8 waves: p=w&3 -> (mtile=p>>1, ntile=p&1); khalf=w>>2 splits K.
// h exchange: producer stores write-through (sc0 sc1) -> waitcnt -> barrier ->
// flag store (sc0 sc1). Consumers poll flags with sc0 sc1 loads, then read h
// with PLAIN cached loads (first-touch-after-completion => never stale).
__global__ __launch_bounds__(NTHR, 2) void lstm_persist(
    const unsigned short* __restrict__ xbf,   // [T][B][I] bf16
    const unsigned short* __restrict__ whh,   // [4H][H] bf16
    const unsigned short* __restrict__ wih,   // [4H][I] bf16
    const float* __restrict__ bsum,           // [4H]
    unsigned short* __restrict__ hs,          // [T][B][H] bf16
    u32* __restrict__ flg)                    // 256 flags, stride 16 u32 (64B)
{
    __shared__ float glp[2][32][33];          // 8448 B

    const int bid = blockIdx.x;
    const int gid = bid >> 7;
    const int lb  = bid & 127;
    const int cg0 = lb * 8;
    const int gb0 = gid * 32;
    const int tid = threadIdx.x;
    const int w   = tid >> 6;
    const int l   = tid & 63;
    const int l16 = l & 15;
    const int lk8 = (l >> 4) << 3;
    const int p     = w & 3;
    const int mtile = p >> 1;
    const int ntile = p & 1;
    const int khalf = w >> 2;

    const int nrow = ntile * 16 + l16;                       // local gate-row
    const int grow = (nrow >> 3) * 1024 + cg0 + (nrow & 7);  // global gate-row
    const int arow = gb0 + mtile * 16 + l16;                 // batch row (A frag)

    // ---- W fragments -> VGPRs, resident for all 512 steps ----
    bfrag8 wh[16];
    bfrag8 wx[4];
    {
        const unsigned short* wp = whh + (size_t)grow * H_ + khalf * 512 + lk8;
        #pragma unroll
        for (int kt = 0; kt < 16; ++kt) wh[kt] = *(const bfrag8*)(wp + kt * 32);
        const unsigned short* xp = wih + (size_t)grow * I_ + khalf * 128 + lk8;
        #pragma unroll
        for (int kt = 0; kt < 4; ++kt) wx[kt] = *(const bfrag8*)(xp + kt * 32);
    }

    // ---- pointwise state: threads 0..127 own (batch pb, col pair pjp) ----
    const int pb  = tid >> 2;
    const int pjp = (tid & 3) * 2;
    float c0 = 0.f, c1 = 0.f;
    float bias_g[4][2];
    if (tid < 128) {
        #pragma unroll
        for (int g = 0; g < 4; ++g) {
            bias_g[g][0] = bsum[g * 1024 + cg0 + pjp];
            bias_g[g][1] = bsum[g * 1024 + cg0 + pjp + 1];
        }
    }

    u32* myflag = flg + (gid * 128 + lb) * 16;
    const u32* pf0 = flg + (gid * 128 + l) * 16;        // lane l polls flag l
    const u32* pf1 = flg + (gid * 128 + l + 64) * 16;   // and flag l+64

    const int mrow = (l >> 4) * 4;   // D: col=lane&15, row=(lane>>4)*4+reg [m89/m91]

    __syncthreads();

    for (int t = 0; t < T_; ++t) {
        f32x4 accA = {0.f, 0.f, 0.f, 0.f};
        f32x4 accB = {0.f, 0.f, 0.f, 0.f};

        // ---- x contribution (independent of h) — overlaps barrier skew ----
        {
            const unsigned short* ap =
                xbf + (size_t)t * (B_ * I_) + (size_t)arow * I_ + khalf * 128 + lk8;
            #pragma unroll
            for (int kt = 0; kt < 4; ++kt) {
                bfrag8 a = *(const bfrag8*)(ap + kt * 32);
                accA = __builtin_amdgcn_mfma_f32_16x16x32_bf16(a, wx[kt], accA, 0, 0, 0);
            }
        }

        if (t > 0) {
            // ---- wait for all 128 producers of h(t-1) ----
            if (w == 0) {
                const u32 tgt = (u32)t;
                while (true) {
                    u32 a, b;
                    poll2_u32(pf0, pf1, a, b);
                    if (__all(a >= tgt && b >= tgt)) break;
                    __builtin_amdgcn_s_sleep(1);
                }
            }
            __syncthreads();

            // ---- h(t-1) @ W_hh — plain cached loads (first touch is fresh) ----
            const unsigned short* ap = hs + (size_t)(t - 1) * (B_ * H_) +
                                       (size_t)arow * H_ + khalf * 512 + lk8;
            #pragma unroll
            for (int kt = 0; kt < 8; ++kt) {
                bfrag8 a = *(const bfrag8*)(ap + kt * 32);
                accA = __builtin_amdgcn_mfma_f32_16x16x32_bf16(a, wh[kt], accA, 0, 0, 0);
            }
            #pragma unroll
            for (int kt = 8; kt < 16; ++kt) {
                bfrag8 a = *(const bfrag8*)(ap + kt * 32);
                accB = __builtin_amdgcn_mfma_f32_16x16x32_bf16(a, wh[kt], accB, 0, 0, 0);
            }
        }

        // ---- exchange partial gate pre-activations ----
        #pragma unroll
        for (int r = 0; r < 4; ++r)
            glp[khalf][mtile * 16 + mrow + r][ntile * 16 + l16] = accA[r] + accB[r];
        __syncthreads();

        // ---- pointwise LSTM cell update (c in registers forever) ----
        if (tid < 128) {
            float pre[4][2];
            #pragma unroll
            for (int g = 0; g < 4; ++g) {
                int n = g * 8 + pjp;
                pre[g][0] = glp[0][pb][n]     + glp[1][pb][n]     + bias_g[g][0];
                pre[g][1] = glp[0][pb][n + 1] + glp[1][pb][n + 1] + bias_g[g][1];
            }
            float i0 = sigmoid_fast(pre[0][0]), i1 = sigmoid_fast(pre[0][1]);
            float f0 = sigmoid_fast(pre[1][0]), f1 = sigmoid_fast(pre[1][1]);
            float g0 = tanh_fast(pre[2][0]),    g1 = tanh_fast(pre[2][1]);
            float o0 = sigmoid_fast(pre[3][0]), o1 = sigmoid_fast(pre[3][1]);
            c0 = f0 * c0 + i0 * g0;
            c1 = f1 * c1 + i1 * g1;
            float h0 = o0 * tanh_fast(c0);
            float h1 = o1 * tanh_fast(c1);
            u32 hv = ((u32)f2bf(h1) << 16) | (u32)f2bf(h0);
            u32* hp = (u32*)(hs + (size_t)t * (B_ * H_) +
                             (size_t)(gb0 + pb) * H_ + cg0 + pjp);
            store_wt_u32(hp, hv);
            // Drain this wave's write-through stores to the coherence point
            // BEFORE the barrier, so the flag store below is globally ordered
            // after all 128 h-dwords of this block.
            asm volatile("s_waitcnt vmcnt(0)" ::: "memory");
        }
        __syncthreads();

        if (tid == 0) store_wt_u32(myflag, (u32)(t + 1));
    }
}

// out[TB][256] = hs[TB][1024] @ W_out[256][1024]^T + b_out
__global__ __launch_bounds__(256) void out_gemm(
    const unsigned short* __restrict__ hs,
    const unsigned short* __restrict__ wout,
    const float* __restrict__ bout,
    float* __restrict__ out)
{
    const int bid  = blockIdx.x;
    const int nblk = bid & 3;
    const int mblk = bid >> 2;
    const int tid  = threadIdx.x;
    const int w    = tid >> 6;
    const int l    = tid & 63;
    const int l16  = l & 15;
    const int lk8  = (l >> 4) << 3;

    const int m0 = mblk * 64 + w * 16;
    const int n0 = nblk * 64;

    f32x4 acc[4] = {};
    const unsigned short* __restrict__ arow = hs + (size_t)(m0 + l16) * H_;
#pragma unroll 2
    for (int kt = 0; kt < 32; ++kt) {
        int k = kt * 32 + lk8;
        bfrag8 af = *(const bfrag8*)(arow + k);
#pragma unroll
        for (int nt = 0; nt < 4; ++nt) {
            bfrag8 bf = *(const bfrag8*)(wout + (size_t)(n0 + nt * 16 + l16) * H_ + k);
            acc[nt] = __builtin_amdgcn_mfma_f32_16x16x32_bf16(af, bf, acc[nt], 0, 0, 0);
        }
    }
    const int mrow = (l >> 4) * 4;
#pragma unroll
    for (int nt = 0; nt < 4; ++nt) {
        int o = n0 + nt * 16 + l16;
        float bb = bout[o];
#pragma unroll
        for (int r = 0; r < 4; ++r) {
            out[(size_t)(m0 + mrow + r) * O_ + o] = acc[nt][r] + bb;
        }
    }
}

extern "C" void kernel_launch(void* const* d_in, const int* in_sizes, int n_in,
                              void* d_out, int out_size, void* d_ws, size_t ws_size,
                              hipStream_t stream) {
    const float* x     = (const float*)d_in[0];
    const float* W_ih  = (const float*)d_in[1];
    const float* W_hh  = (const float*)d_in[2];
    const float* b_ih  = (const float*)d_in[3];
    const float* b_hh  = (const float*)d_in[4];
    const float* W_out = (const float*)d_in[5];
    const float* b_out = (const float*)d_in[6];
    float* out = (float*)d_out;

    char* ws = (char*)d_ws;
    unsigned short* hs   = (unsigned short*)(ws);              // 67,108,864 B
    unsigned short* xbf  = (unsigned short*)(ws + 67108864);   // 16,777,216 B
    unsigned short* whh  = (unsigned short*)(ws + 83886080);   //  8,388,608 B
    unsigned short* wih  = (unsigned short*)(ws + 92274688);   //  2,097,152 B
    unsigned short* wout = (unsigned short*)(ws + 94371840);   //    524,288 B
    float*          bsum = (float*)         (ws + 94896128);   //     16,384 B
    u32*            flg  = (u32*)           (ws + 94912512);   //     16,384 B

    cvt_bf16<<<2048, 256, 0, stream>>>(x,     xbf,  T_ * B_ * I_);
    cvt_bf16<<<2048, 256, 0, stream>>>(W_hh,  whh,  G4_ * H_);
    cvt_bf16<<<1024, 256, 0, stream>>>(W_ih,  wih,  G4_ * I_);
    cvt_bf16<<<256,  256, 0, stream>>>(W_out, wout, O_ * H_);
    bias_sum_k<<<16, 256, 0, stream>>>(b_ih, b_hh, bsum, G4_);
    hipMemsetAsync(flg, 0, 16384, stream);

    void* args[] = {(void*)&xbf, (void*)&whh, (void*)&wih, (void*)&bsum,
                    (void*)&hs, (void*)&flg};
    hipLaunchCooperativeKernel((const void*)lstm_persist, dim3(NBLK), dim3(NTHR),
                               args, 0, stream);

    out_gemm<<<2048, 256, 0, stream>>>(hs, wout, b_out, out);
}

// Round 5
// 3643.893 us; speedup vs baseline: 3.6510x; 1.0256x over previous
//
#include <hip/hip_runtime.h>

#define T_ 512
#define B_ 64
#define I_ 256
#define H_ 1024
#define G4_ 4096
#define O_ 256

#define NBLK 256
#define NTHR 512

typedef short bfrag8 __attribute__((ext_vector_type(8)));   // 8 bf16 (4 VGPRs)
typedef float f32x4 __attribute__((ext_vector_type(4)));
typedef unsigned int u32;

// f32 -> bf16 bits, round-to-nearest-even
__device__ __forceinline__ unsigned short f2bf(float f) {
    unsigned int u = __builtin_bit_cast(unsigned int, f);
    u = (u + 0x7fffu + ((u >> 16) & 1u)) >> 16;
    return (unsigned short)u;
}

__device__ __forceinline__ float sigmoid_fast(float x) {
    return 1.0f / (1.0f + __expf(-x));
}
__device__ __forceinline__ float tanh_fast(float x) {
    x = fminf(fmaxf(x, -15.0f), 15.0f);
    float e = __expf(2.0f * x);
    return (e - 1.0f) / (e + 1.0f);
}

// Write-through (coherence-point) store; bypasses non-coherent L2s.
__device__ __forceinline__ void store_wt_u32(u32* p, u32 v) {
    asm volatile("global_store_dword %0, %1, off sc0 sc1" :: "v"(p), "v"(v) : "memory");
}
// Uncached poll load (flags/counters change every step; must never be cached).
__device__ __forceinline__ u32 poll1_u32(const u32* p) {
    u32 v;
    asm volatile("global_load_dword %0, %1, off sc0 sc1\n\t"
                 "s_waitcnt vmcnt(0)"
                 : "=&v"(v) : "v"(p) : "memory");
    return v;
}
// Volatile asm load: cannot be rematerialized/sunk -> value stays in VGPRs.
__device__ __forceinline__ bfrag8 pin_load_frag(const unsigned short* p) {
    bfrag8 r;
    asm volatile("global_load_dwordx4 %0, %1, off" : "=&v"(r) : "v"(p));
    return r;
}

__global__ void cvt_bf16(const float* __restrict__ in, unsigned short* __restrict__ out, int n) {
    int i = blockIdx.x * blockDim.x + threadIdx.x;
    int st = gridDim.x * blockDim.x;
    for (; i < n; i += st) out[i] = f2bf(in[i]);
}

__global__ void bias_sum_k(const float* __restrict__ a, const float* __restrict__ b,
                           float* __restrict__ o, int n) {
    int i = blockIdx.x * blockDim.x + threadIdx.x;
    if (i < n) o[i] = a[i] + b[i];
}

// Persistent LSTM recurrence. 256 blocks x 512 threads (cooperative).
// Group g = bid>>7 owns batch rows [32g,32g+32); groups are independent.
// Block lb = bid&127 owns h-cols [8lb,8lb+8) x 4 gates = 32 gate-rows; that
// W slice is PINNED in VGPRs (20 bfrag8/wave, volatile-asm loaded) for all T.
// 8 waves: p=w&3 -> (mtile=p>>1, ntile=p&1); khalf=w>>2 splits K.
// Exchange protocol per step t:
//   waves0/1: pointwise -> h(t) store (sc0 sc1) -> s_waitcnt vmcnt(0)
//             -> lane0: atomic_add(+1, AGENT) on counter line (lb&3) of group
//   all:      next iter: x-MFMA(t+1); wave0 polls 4 counter lines (lane l ->
//             line l&3, sc0 sc1) until all >= 64*(t+1); __syncthreads;
//             h(t) via PLAIN cached loads (first-touch-after-completion).
__global__ __launch_bounds__(NTHR, 2) void lstm_persist(
    const unsigned short* __restrict__ xbf,   // [T][B][I] bf16
    const unsigned short* __restrict__ whh,   // [4H][H] bf16
    const unsigned short* __restrict__ wih,   // [4H][I] bf16
    const float* __restrict__ bsum,           // [4H]
    unsigned short* __restrict__ hs,          // [T][B][H] bf16
    u32* __restrict__ cnt)                    // 2 groups x 4 lines (16 u32 stride)
{
    __shared__ float glp[2][32][33];          // 8448 B

    const int bid = blockIdx.x;
    const int gid = bid >> 7;
    const int lb  = bid & 127;
    const int cg0 = lb * 8;
    const int gb0 = gid * 32;
    const int tid = threadIdx.x;
    const int w   = tid >> 6;
    const int l   = tid & 63;
    const int l16 = l & 15;
    const int lk8 = (l >> 4) << 3;
    const int p     = w & 3;
    const int mtile = p >> 1;
    const int ntile = p & 1;
    const int khalf = w >> 2;

    const int nrow = ntile * 16 + l16;                       // local gate-row
    const int grow = (nrow >> 3) * 1024 + cg0 + (nrow & 7);  // global gate-row
    const int arow = gb0 + mtile * 16 + l16;                 // batch row (A frag)

    // ---- W fragments pinned in VGPRs for all 512 steps ----
    bfrag8 wh[16];
    bfrag8 wx[4];
    {
        const unsigned short* wp = whh + (size_t)grow * H_ + khalf * 512 + lk8;
        #pragma unroll
        for (int kt = 0; kt < 16; ++kt) wh[kt] = pin_load_frag(wp + kt * 32);
        const unsigned short* xp = wih + (size_t)grow * I_ + khalf * 128 + lk8;
        #pragma unroll
        for (int kt = 0; kt < 4; ++kt) wx[kt] = pin_load_frag(xp + kt * 32);
        asm volatile("s_waitcnt vmcnt(0)" ::: "memory");
        __builtin_amdgcn_sched_barrier(0);
    }

    // ---- pointwise state: threads 0..127 own (batch pb, col pair pjp) ----
    const int pb  = tid >> 2;
    const int pjp = (tid & 3) * 2;
    float c0 = 0.f, c1 = 0.f;
    float bias_g[4][2];
    if (tid < 128) {
        #pragma unroll
        for (int g = 0; g < 4; ++g) {
            bias_g[g][0] = bsum[g * 1024 + cg0 + pjp];
            bias_g[g][1] = bsum[g * 1024 + cg0 + pjp + 1];
        }
    }

    u32* mycnt = cnt + (gid * 4 + (lb & 3)) * 16;      // producer add target
    const u32* pollp = cnt + (gid * 4 + (l & 3)) * 16; // lane l polls line l&3

    const int mrow = (l >> 4) * 4;   // D: col=lane&15, row=(lane>>4)*4+reg [m89/m91]

    __syncthreads();

    for (int t = 0; t < T_; ++t) {
        f32x4 accA = {0.f, 0.f, 0.f, 0.f};
        f32x4 accB = {0.f, 0.f, 0.f, 0.f};

        // ---- x contribution (independent of h) — issued before the wait ----
        {
            const unsigned short* ap =
                xbf + (size_t)t * (B_ * I_) + (size_t)arow * I_ + khalf * 128 + lk8;
            #pragma unroll
            for (int kt = 0; kt < 4; ++kt) {
                bfrag8 a = *(const bfrag8*)(ap + kt * 32);
                accA = __builtin_amdgcn_mfma_f32_16x16x32_bf16(a, wx[kt], accA, 0, 0, 0);
            }
        }

        if (t > 0) {
            // ---- wait for all 256 producer-adds of h(t-1): 64 per line ----
            if (w == 0) {
                const u32 tgt = 64u * (u32)t;
                while (true) {
                    u32 v = poll1_u32(pollp);
                    if (__all(v >= tgt)) break;
                    __builtin_amdgcn_s_sleep(1);
                }
            }
            __syncthreads();

            // ---- h(t-1) @ W_hh — plain cached loads (first touch is fresh) ----
            const unsigned short* ap = hs + (size_t)(t - 1) * (B_ * H_) +
                                       (size_t)arow * H_ + khalf * 512 + lk8;
            #pragma unroll
            for (int kt = 0; kt < 8; ++kt) {
                bfrag8 a = *(const bfrag8*)(ap + kt * 32);
                accA = __builtin_amdgcn_mfma_f32_16x16x32_bf16(a, wh[kt], accA, 0, 0, 0);
            }
            #pragma unroll
            for (int kt = 8; kt < 16; ++kt) {
                bfrag8 a = *(const bfrag8*)(ap + kt * 32);
                accB = __builtin_amdgcn_mfma_f32_16x16x32_bf16(a, wh[kt], accB, 0, 0, 0);
            }
        }

        // ---- exchange partial gate pre-activations ----
        #pragma unroll
        for (int r = 0; r < 4; ++r)
            glp[khalf][mtile * 16 + mrow + r][ntile * 16 + l16] = accA[r] + accB[r];
        __syncthreads();

        // ---- pointwise update + publish (waves 0,1 only; others run ahead) ----
        if (tid < 128) {
            float pre[4][2];
            #pragma unroll
            for (int g = 0; g < 4; ++g) {
                int n = g * 8 + pjp;
                pre[g][0] = glp[0][pb][n]     + glp[1][pb][n]     + bias_g[g][0];
                pre[g][1] = glp[0][pb][n + 1] + glp[1][pb][n + 1] + bias_g[g][1];
            }
            float i0 = sigmoid_fast(pre[0][0]), i1 = sigmoid_fast(pre[0][1]);
            float f0 = sigmoid_fast(pre[1][0]), f1 = sigmoid_fast(pre[1][1]);
            float g0 = tanh_fast(pre[2][0]),    g1 = tanh_fast(pre[2][1]);
            float o0 = sigmoid_fast(pre[3][0]), o1 = sigmoid_fast(pre[3][1]);
            c0 = f0 * c0 + i0 * g0;
            c1 = f1 * c1 + i1 * g1;
            float h0 = o0 * tanh_fast(c0);
            float h1 = o1 * tanh_fast(c1);
            u32 hv = ((u32)f2bf(h1) << 16) | (u32)f2bf(h0);
            u32* hp = (u32*)(hs + (size_t)t * (B_ * H_) +
                             (size_t)(gb0 + pb) * H_ + cg0 + pjp);
            store_wt_u32(hp, hv);
            // Drain this wave's write-through h stores to the coherence point,
            // then publish: +1 on this block's counter line (per wave 0 and 1).
            asm volatile("s_waitcnt vmcnt(0)" ::: "memory");
            if ((tid & 63) == 0)
                __hip_atomic_fetch_add(mycnt, 1u, __ATOMIC_RELAXED,
                                       __HIP_MEMORY_SCOPE_AGENT);
        }
        // No barrier here: waves 2-7 proceed to t+1 x-MFMA; the post-poll
        // __syncthreads at t+1 orders glp(t) reads before glp(t+1) writes.
    }
}

// out[TB][256] = hs[TB][1024] @ W_out[256][1024]^T + b_out
__global__ __launch_bounds__(256) void out_gemm(
    const unsigned short* __restrict__ hs,
    const unsigned short* __restrict__ wout,
    const float* __restrict__ bout,
    float* __restrict__ out)
{
    const int bid  = blockIdx.x;
    const int nblk = bid & 3;
    const int mblk = bid >> 2;
    const int tid  = threadIdx.x;
    const int w    = tid >> 6;
    const int l    = tid & 63;
    const int l16  = l & 15;
    const int lk8  = (l >> 4) << 3;

    const int m0 = mblk * 64 + w * 16;
    const int n0 = nblk * 64;

    f32x4 acc[4] = {};
    const unsigned short* __restrict__ arow = hs + (size_t)(m0 + l16) * H_;
#pragma unroll 2
    for (int kt = 0; kt < 32; ++kt) {
        int k = kt * 32 + lk8;
        bfrag8 af = *(const bfrag8*)(arow + k);
#pragma unroll
        for (int nt = 0; nt < 4; ++nt) {
            bfrag8 bf = *(const bfrag8*)(wout + (size_t)(n0 + nt * 16 + l16) * H_ + k);
            acc[nt] = __builtin_amdgcn_mfma_f32_16x16x32_bf16(af, bf, acc[nt], 0, 0, 0);
        }
    }
    const int mrow = (l >> 4) * 4;
#pragma unroll
    for (int nt = 0; nt < 4; ++nt) {
        int o = n0 + nt * 16 + l16;
        float bb = bout[o];
#pragma unroll
        for (int r = 0; r < 4; ++r) {
            out[(size_t)(m0 + mrow + r) * O_ + o] = acc[nt][r] + bb;
        }
    }
}

extern "C" void kernel_launch(void* const* d_in, const int* in_sizes, int n_in,
                              void* d_out, int out_size, void* d_ws, size_t ws_size,
                              hipStream_t stream) {
    const float* x     = (const float*)d_in[0];
    const float* W_ih  = (const float*)d_in[1];
    const float* W_hh  = (const float*)d_in[2];
    const float* b_ih  = (const float*)d_in[3];
    const float* b_hh  = (const float*)d_in[4];
    const float* W_out = (const float*)d_in[5];
    const float* b_out = (const float*)d_in[6];
    float* out = (float*)d_out;

    char* ws = (char*)d_ws;
    unsigned short* hs   = (unsigned short*)(ws);              // 67,108,864 B
    unsigned short* xbf  = (unsigned short*)(ws + 67108864);   // 16,777,216 B
    unsigned short* whh  = (unsigned short*)(ws + 83886080);   //  8,388,608 B
    unsigned short* wih  = (unsigned short*)(ws + 92274688);   //  2,097,152 B
    unsigned short* wout = (unsigned short*)(ws + 94371840);   //    524,288 B
    float*          bsum = (float*)         (ws + 94896128);   //     16,384 B
    u32*            cnt  = (u32*)           (ws + 94912512);   //        512 B

    cvt_bf16<<<2048, 256, 0, stream>>>(x,     xbf,  T_ * B_ * I_);
    cvt_bf16<<<2048, 256, 0, stream>>>(W_hh,  whh,  G4_ * H_);
    cvt_bf16<<<1024, 256, 0, stream>>>(W_ih,  wih,  G4_ * I_);
    cvt_bf16<<<256,  256, 0, stream>>>(W_out, wout, O_ * H_);
    bias_sum_k<<<16, 256, 0, stream>>>(b_ih, b_hh, bsum, G4_);
    hipMemsetAsync(cnt, 0, 512, stream);

    void* args[] = {(void*)&xbf, (void*)&whh, (void*)&wih, (void*)&bsum,
                    (void*)&hs, (void*)&cnt};
    hipLaunchCooperativeKernel((const void*)lstm_persist, dim3(NBLK), dim3(NTHR),
                               args, 0, stream);

    out_gemm<<<2048, 256, 0, stream>>>(hs, wout, b_out, out);
}